// Round 11
// baseline (326.930 us; speedup 1.0000x reference)
//
#include <hip/hip_runtime.h>
#include <hip/hip_bf16.h>
#include <stdint.h>

#define BS 8
#define TT 4096
#define DI 1024
#define DH 1024
#define DO 1024
#define M1 (BS*TT)      // 32768
#define NC 64           // scan chunks
#define CL (TT/NC)      // 64

typedef __attribute__((ext_vector_type(8))) __bf16 bf16x8;
typedef __attribute__((ext_vector_type(4))) __bf16 bf16x4;
typedef __attribute__((ext_vector_type(4))) float f32x4;

// ---------- transpose + convert: dst[n][k] = (bf16) src[k][n] ----------
__global__ void transp_conv_kernel(const float* __restrict__ src, __bf16* __restrict__ dst,
                                   int K, int N) {
    __shared__ float tile[32][33];
    const int tx = threadIdx.x & 31;
    const int ty = threadIdx.x >> 5;
    const int k0 = blockIdx.x * 32;
    const int n0 = blockIdx.y * 32;
    #pragma unroll
    for (int i = 0; i < 32; i += 8)
        tile[ty + i][tx] = src[(size_t)(k0 + ty + i) * N + n0 + tx];
    __syncthreads();
    #pragma unroll
    for (int i = 0; i < 32; i += 8)
        dst[(size_t)(n0 + ty + i) * K + k0 + tx] = (__bf16)tile[tx][ty + i];
}

// ---------- 256x256 8-phase bf16 GEMM (T2+T3+T4+T5): C = A[M][K] * Bt[N][K]^T ----------
// Schedule identical to rounds 7/9/10 (proven). OUTF32=0 (GEMM1): A is FP32 source,
// reg-staged (global_load f32x4 -> cvt -> swizzled ds_write_b64) at the SAME stage
// slots/retirement points as the old gload_lds path; epilogue writes bf16 u + fused
// chunk-end scan sums E. OUTF32=1 (GEMM2): A is bf16, gload_lds staging, fp32 out.
// NOTE (R8 lesson): do NOT spread staging 1-per-phase at 2-tiles-ahead with counted
// lgkm read-ahead — measured 78->130 us, FETCH +40% (L2 thrash + serialization).
template<int OUTF32>
__global__ __launch_bounds__(512, 2) void gemm256_kernel(
    const float* __restrict__ Axf, const __bf16* __restrict__ Ah,
    const __bf16* __restrict__ Bt,
    __bf16* __restrict__ Obf, float* __restrict__ Of,
    const float* __restrict__ Ea, float* __restrict__ Ep,
    int M, int N, int K)
{
    __shared__ __bf16 lds[65536];   // A slots [0,32768), B slots [32768,65536)
    const int tid = threadIdx.x;
    const int wv = tid >> 6;          // 0..7
    const int l  = tid & 63;
    const int sr = wv >> 2;           // row slot 0..1
    const int sc = wv & 3;            // col slot 0..3
    const int lr = l & 15;
    const int lk = (l >> 4) * 8;
    const int xsw = (lr & 7) * 8;                 // read-side swizzle (elems)
    const int ak0 = lk ^ xsw, ak1 = (32 + lk) ^ xsw;
    const int rowBase = blockIdx.x * 256;
    const int colBase = blockIdx.y * 256;
    const int aOff = (sr * 64 + lr) * 64;         // A frag row base (elems, within half slot)
    const int bOff = (sc * 32 + lr) * 64;
    const int csw = ((l & 7) ^ (l >> 3)) * 8;     // source-side pre-swizzle (elems, gload_lds)
    const __bf16* aSrc0 = OUTF32 ? Ah + (size_t)(rowBase + wv * 16 + (l >> 3)) * K + csw : nullptr;
    const __bf16* bSrc0 = Bt + (size_t)(colBase + wv * 16 + (l >> 3)) * K + csw;

    f32x4 acc[2][2][4][2];
    #pragma unroll
    for (int a0 = 0; a0 < 2; a0++)
        #pragma unroll
        for (int b0 = 0; b0 < 2; b0++)
            #pragma unroll
            for (int m = 0; m < 4; m++)
                #pragma unroll
                for (int n = 0; n < 2; n++)
                    acc[a0][b0][m][n] = (f32x4){0.f, 0.f, 0.f, 0.f};

    bf16x8 aF0[4][2], aF1[4][2], bF[2][2];
    f32x4 rA11[4], rA00[4], rA01[4], rA10[4];   // fp32 A staging regs (GEMM1 only)

#define GLD(s, d) __builtin_amdgcn_global_load_lds( \
        (const __attribute__((address_space(1))) void*)(s), \
        (__attribute__((address_space(3))) void*)(d), 16, 0, 0)
#define STAGE_A(buf, half, ktE) do { \
        const __bf16* s_ = aSrc0 + (size_t)(half) * 128 * K + (ktE); \
        __bf16* d_ = &lds[((buf) * 2 + (half)) * 8192 + wv * 1024]; \
        GLD(s_, d_); GLD(s_ + (size_t)8 * K, d_ + 512); } while (0)
#define STAGE_B(buf, half, ktE) do { \
        const __bf16* s_ = bSrc0 + (size_t)(half) * 128 * K + (ktE); \
        __bf16* d_ = &lds[32768 + ((buf) * 2 + (half)) * 8192 + wv * 1024]; \
        GLD(s_, d_); GLD(s_ + (size_t)8 * K, d_ + 512); } while (0)
// fp32 A: 4x global_load f32x4 (rows i*4+(l>>4), cols (l&15)*4 within K-tile) — linear, coalesced
#define ALOAD(REG, half, ktE) do { \
        const float* s_ = Axf + (size_t)(rowBase + (half) * 128 + wv * 16 + (l >> 4)) * K + (ktE) + (l & 15) * 4; \
        REG[0] = *(const f32x4*)(s_); \
        REG[1] = *(const f32x4*)(s_ + (size_t)4 * K); \
        REG[2] = *(const f32x4*)(s_ + (size_t)8 * K); \
        REG[3] = *(const f32x4*)(s_ + (size_t)12 * K); } while (0)
// cvt + swizzled ds_write_b64 x4; dest block (scb^r7) matches gload_lds layout rule
#define AWRITE(REG, buf, half) do { \
        __bf16* db_ = &lds[((buf) * 2 + (half)) * 8192 + wv * 1024]; \
        const int scb_ = (l & 15) >> 1; const int lh_ = (l & 1); \
        _Pragma("unroll") \
        for (int i_ = 0; i_ < 4; i_++) { \
            int r_ = i_ * 4 + (l >> 4); int j_ = r_ >> 3; int r7_ = r_ & 7; \
            int d_ = j_ * 512 + (r7_ * 8 + (scb_ ^ r7_)) * 8 + lh_ * 4; \
            bf16x4 o_; \
            o_[0] = (__bf16)REG[i_][0]; o_[1] = (__bf16)REG[i_][1]; \
            o_[2] = (__bf16)REG[i_][2]; o_[3] = (__bf16)REG[i_][3]; \
            *(bf16x4*)&db_[d_] = o_; } } while (0)
#define LOADA(buf, qr, AF) do { \
        const __bf16* Ab_ = &lds[((buf) * 2 + (qr)) * 8192 + aOff]; \
        _Pragma("unroll") \
        for (int m = 0; m < 4; m++) { \
            AF[m][0] = *(const bf16x8*)&Ab_[m * 1024 + ak0]; \
            AF[m][1] = *(const bf16x8*)&Ab_[m * 1024 + ak1]; } } while (0)
#define LOADB(buf, qc) do { \
        const __bf16* Bb_ = &lds[32768 + ((buf) * 2 + (qc)) * 8192 + bOff]; \
        _Pragma("unroll") \
        for (int n = 0; n < 2; n++) { \
            bF[n][0] = *(const bf16x8*)&Bb_[n * 1024 + ak0]; \
            bF[n][1] = *(const bf16x8*)&Bb_[n * 1024 + ak1]; } } while (0)
#define MMQ(qr, qc, AF) do { \
        __builtin_amdgcn_s_setprio(1); \
        _Pragma("unroll") \
        for (int m = 0; m < 4; m++) \
            _Pragma("unroll") \
            for (int n = 0; n < 2; n++) { \
                acc[qr][qc][m][n] = __builtin_amdgcn_mfma_f32_16x16x32_bf16(AF[m][0], bF[n][0], acc[qr][qc][m][n], 0, 0, 0); \
                acc[qr][qc][m][n] = __builtin_amdgcn_mfma_f32_16x16x32_bf16(AF[m][1], bF[n][1], acc[qr][qc][m][n], 0, 0, 0); } \
        __builtin_amdgcn_s_setprio(0); } while (0)
#define SB __builtin_amdgcn_sched_barrier(0)
#define BAR __builtin_amdgcn_s_barrier()
#define LGKM0 asm volatile("s_waitcnt lgkmcnt(0)" ::: "memory")
#define PH_BAR() do { SB; BAR; LGKM0; SB; } while (0)
#define PHEND() do { SB; BAR; } while (0)
#define VMW(cond) do { if (cond) { asm volatile("s_waitcnt vmcnt(0)" ::: "memory"); } \
                       else      { asm volatile("s_waitcnt vmcnt(4)" ::: "memory"); } } while (0)

    const int NIT = K >> 7;   // 2 K-tiles (of 64) per iteration

    // ---- prologue: K-tile 0 -> buf0, K-tile 1 -> buf1 ----
    if constexpr (!OUTF32) {
        ALOAD(rA00, 0, 0); ALOAD(rA01, 1, 0);
        STAGE_B(0, 0, 0); STAGE_B(0, 1, 0);
        AWRITE(rA00, 0, 0); AWRITE(rA01, 0, 1);       // compiler auto-wait vmcnt(4)
        ALOAD(rA10, 0, 64); ALOAD(rA11, 1, 64);
        STAGE_B(1, 0, 64); STAGE_B(1, 1, 64);
        AWRITE(rA10, 1, 0); AWRITE(rA11, 1, 1);       // compiler auto-wait vmcnt(4)
        SB; LGKM0; BAR;                                // ds_writes visible; B1 (4) in flight
    } else {
        STAGE_A(0, 0, 0); STAGE_A(0, 1, 0); STAGE_B(0, 0, 0); STAGE_B(0, 1, 0);
        STAGE_A(1, 0, 64); STAGE_A(1, 1, 64); STAGE_B(1, 0, 64); STAGE_B(1, 1, 64);
        asm volatile("s_waitcnt vmcnt(8)" ::: "memory");
        BAR;
    }

    for (int it = 0; it < NIT; ++it) {
        const int ktOdd  = (2 * it + 1) * 64;   // this iter's odd K-tile (buf1 half1 fill)
        const int ktEv2  = (2 * it + 2) * 64;   // next even K-tile (buf0)
        const int ktOdd2 = (2 * it + 3) * 64;   // next odd K-tile (buf1 half0 fill)
        const bool last = (it == NIT - 1);
        // P1: Q(0,0) buf0 — frag A0(8)+B0(4); stage slot A(1,1)
        LOADA(0, 0, aF0); LOADB(0, 0);
        if constexpr (!OUTF32) { if (it > 0) ALOAD(rA11, 1, ktOdd); }
        else                   { if (it > 0) STAGE_A(1, 1, ktOdd); }
        PH_BAR(); MMQ(0, 0, aF0); PHEND();
        // P2: Q(1,0) buf0 — frag A1(8); stage B(1,1)
        LOADA(0, 1, aF1);
        if (it > 0) STAGE_B(1, 1, ktOdd);
        PH_BAR(); MMQ(1, 0, aF1); PHEND();
        // P3: Q(1,1) buf0 — frag B1(4); stage B(0,0)
        LOADB(0, 1);
        if (!last) STAGE_B(0, 0, ktEv2);
        PH_BAR(); MMQ(1, 1, aF1); PHEND();
        // P4: Q(0,1) buf0 — no frag reads; stage slot A(0,0); group wait +
        //     AWRITE(1,0) (prev-P8 loads retired by this vmcnt)
        if constexpr (!OUTF32) { if (!last) ALOAD(rA00, 0, ktEv2); }
        else                   { if (!last) STAGE_A(0, 0, ktEv2); }
        PH_BAR(); MMQ(0, 1, aF0);
        SB; VMW(last);
        if constexpr (!OUTF32) { if (it > 0) AWRITE(rA10, 1, 0); }
        LGKM0; BAR;
        // P5: Q(0,0) buf1 — frag A0+B0; AWRITE(1,1) (loads retired @P4); stage slot A(0,1)
        LOADA(1, 0, aF0); LOADB(1, 0);
        if constexpr (!OUTF32) {
            if (it > 0) AWRITE(rA11, 1, 1);
            if (!last) ALOAD(rA01, 1, ktEv2);
        } else {
            if (!last) STAGE_A(0, 1, ktEv2);
        }
        PH_BAR(); MMQ(0, 0, aF0); PHEND();
        // P6: Q(1,0) buf1 — frag A1; stage B(0,1)
        LOADA(1, 1, aF1);
        if (!last) STAGE_B(0, 1, ktEv2);
        PH_BAR(); MMQ(1, 0, aF1); PHEND();
        // P7: Q(1,1) buf1 — frag B1; stage B(1,0)
        LOADB(1, 1);
        if (!last) STAGE_B(1, 0, ktOdd2);
        PH_BAR(); MMQ(1, 1, aF1); PHEND();
        // P8: Q(0,1) buf1 — no frag reads; stage slot A(1,0); group wait +
        //     AWRITE(0,0),(0,1) (P4/P5 loads retired by this vmcnt)
        if constexpr (!OUTF32) { if (!last) ALOAD(rA10, 0, ktOdd2); }
        else                   { if (!last) STAGE_A(1, 0, ktOdd2); }
        PH_BAR(); MMQ(0, 1, aF0);
        SB; VMW(last);
        if constexpr (!OUTF32) { if (!last) { AWRITE(rA00, 0, 0); AWRITE(rA01, 0, 1); } }
        LGKM0; BAR;
    }

    // epilogue: C/D layout col=lane&15, row=(lane>>4)*4+j [m89]
    #pragma unroll
    for (int qr = 0; qr < 2; qr++)
        #pragma unroll
        for (int qc = 0; qc < 2; qc++)
            #pragma unroll
            for (int m = 0; m < 4; m++)
                #pragma unroll
                for (int n = 0; n < 2; n++)
                    #pragma unroll
                    for (int j = 0; j < 4; j++) {
                        int row = rowBase + qr * 128 + sr * 64 + m * 16 + (l >> 4) * 4 + j;
                        int col = colBase + qc * 128 + sc * 32 + n * 16 + lr;
                        size_t idx = (size_t)row * N + col;
                        if constexpr (OUTF32) Of[idx] = acc[qr][qc][m][n][j];
                        else                  Obf[idx] = (__bf16)acc[qr][qc][m][n][j];
                    }

    // fused scan1 (GEMM1 only): E[b,k,ch] = sum_{dt=0}^{63} a_ch^(63-dt) * u[t0+dt,ch]
    if constexpr (!OUTF32) {
        const int hi = l >> 4;
        const int bb = rowBase >> 12;            // row / TT
        #pragma unroll
        for (int qr = 0; qr < 2; qr++) {
            const int r0 = rowBase + qr * 128 + sr * 64;
            const int kch = (r0 & (TT - 1)) >> 6;          // chunk index within batch
            #pragma unroll
            for (int qc = 0; qc < 2; qc++)
                #pragma unroll
                for (int n = 0; n < 2; n++) {
                    const int ch = colBase + qc * 128 + sc * 32 + n * 16 + lr;
                    const float av = Ea[ch];
                    const float a2 = av * av, a4 = a2 * a2;
                    const float a12 = a4 * a4 * a4;
                    float w = 1.f;
                    if (hi < 3) w *= a4;
                    if (hi < 2) w *= a4;
                    if (hi < 1) w *= a4;                   // a^(4*(3-hi))
                    float e = 0.f;
                    #pragma unroll
                    for (int m = 3; m >= 0; --m) {
                        #pragma unroll
                        for (int j = 3; j >= 0; --j) {
                            e += w * acc[qr][qc][m][n][j];
                            w *= av;
                        }
                        w *= a12;
                    }
                    e += __shfl_xor(e, 16);
                    e += __shfl_xor(e, 32);
                    if (hi == 0)
                        Ep[((size_t)(bb * NC + kch)) * DH + ch] = e;
                }
        }
    }
#undef GLD
#undef STAGE_A
#undef STAGE_B
#undef ALOAD
#undef AWRITE
#undef LOADA
#undef LOADB
#undef MMQ
#undef SB
#undef BAR
#undef LGKM0
#undef PH_BAR
#undef PHEND
#undef VMW
}

// ---------- scan pass 2: combine chunk carries ----------
__global__ void scan2_kernel(const float* __restrict__ E, const float* __restrict__ a,
                             float* __restrict__ Cc) {
    int g = blockIdx.x * blockDim.x + threadIdx.x;
    int ch = g & (DH - 1);
    int b = g >> 10;
    float av = a[ch];
    float aL = av;
    #pragma unroll
    for (int i = 0; i < 6; i++) aL *= aL;            // a^64 = a^CL
    float carry = 0.f;
    for (int k = 0; k < NC; k++) {
        size_t idx = ((size_t)(b * NC + k)) * DH + ch;
        Cc[idx] = carry;
        carry = aL * carry + E[idx];
    }
}

// ---------- scan pass 3: recompute local scan + apply carry, write bf16 in place ----------
__global__ void scan3_kernel(__bf16* __restrict__ u, const float* __restrict__ a,
                             const float* __restrict__ Cc) {
    int g = blockIdx.x * blockDim.x + threadIdx.x;
    int c4 = g & 255;
    int rest = g >> 8;
    int k = rest & (NC - 1);
    int b = rest >> 6;
    int ch = c4 * 4;
    f32x4 av = { a[ch], a[ch + 1], a[ch + 2], a[ch + 3] };
    f32x4 p = *(const f32x4*)&Cc[((size_t)(b * NC + k)) * DH + ch];
    f32x4 h = {0.f, 0.f, 0.f, 0.f};
    size_t base = ((size_t)(b * TT + k * CL)) * DH + ch;
    for (int t = 0; t < CL; t++) {
        size_t idx = base + (size_t)t * DH;
        bf16x4 v = *(bf16x4*)&u[idx];
        h[0] = h[0] * av[0] + (float)v[0];
        h[1] = h[1] * av[1] + (float)v[1];
        h[2] = h[2] * av[2] + (float)v[2];
        h[3] = h[3] * av[3] + (float)v[3];
        p[0] *= av[0]; p[1] *= av[1]; p[2] *= av[2]; p[3] *= av[3];
        bf16x4 o;
        o[0] = (__bf16)(h[0] + p[0]);
        o[1] = (__bf16)(h[1] + p[1]);
        o[2] = (__bf16)(h[2] + p[2]);
        o[3] = (__bf16)(h[3] + p[3]);
        *(bf16x4*)&u[idx] = o;
    }
}

extern "C" void kernel_launch(void* const* d_in, const int* in_sizes, int n_in,
                              void* d_out, int out_size, void* d_ws, size_t ws_size,
                              hipStream_t stream) {
    const float* x = (const float*)d_in[0];
    const float* a = (const float*)d_in[1];
    const float* b = (const float*)d_in[2];
    const float* c = (const float*)d_in[3];
    float* y = (float*)d_out;

    // workspace: 68 MiB (proven safe)
    char* ws = (char*)d_ws;
    size_t off = 0;
    __bf16* u  = (__bf16*)(ws + off); off += (size_t)M1 * DH * 2;   // 64 MiB
    __bf16* bT = (__bf16*)(ws + off); off += (size_t)DI * DH * 2;   // 2 MiB
    __bf16* cT = (__bf16*)(ws + off); off += (size_t)DH * DO * 2;   // 2 MiB
    if (ws_size < off) return;

    // scratch inside d_out (dead before gemm2 writes y): E (2 MiB) + Cc (2 MiB)
    float* E  = (float*)d_out;
    float* Cc = E + (size_t)BS * NC * DH;

    transp_conv_kernel<<<dim3(DI / 32, DH / 32), 256, 0, stream>>>(b, bT, DI, DH);
    transp_conv_kernel<<<dim3(DH / 32, DO / 32), 256, 0, stream>>>(c, cT, DH, DO);
    // u = bf16(x @ b), A reg-staged from fp32 x, fused chunk-end scan sums E
    gemm256_kernel<0><<<dim3(M1 / 256, DH / 256), 512, 0, stream>>>(x, nullptr, bT, u, nullptr, a, E, M1, DH, DI);
    // chunked diagonal linear scan over T (in place on u)
    scan2_kernel<<<(BS * DH) / 256, 256, 0, stream>>>(E, a, Cc);
    scan3_kernel<<<(BS * NC * (DH / 4)) / 256, 256, 0, stream>>>(u, a, Cc);
    // y = hs @ c
    gemm256_kernel<1><<<dim3(M1 / 256, DO / 256), 512, 0, stream>>>(nullptr, u, cT, nullptr, y, nullptr, nullptr, M1, DO, DH);
}

// Round 13
// 218.576 us; speedup vs baseline: 1.4957x; 1.4957x over previous
//
#include <hip/hip_runtime.h>
#include <hip/hip_bf16.h>
#include <stdint.h>

#define BS 8
#define TT 4096
#define DI 1024
#define DH 1024
#define DO 1024
#define M1 (BS*TT)      // 32768
#define NC 64           // scan chunks
#define CL (TT/NC)      // 64

typedef __attribute__((ext_vector_type(8))) __bf16 bf16x8;
typedef __attribute__((ext_vector_type(4))) __bf16 bf16x4;
typedef __attribute__((ext_vector_type(4))) float f32x4;

// ---------- fp32 -> bf16 flat conversion ----------
__global__ void conv_bf16_kernel(const float* __restrict__ in, __bf16* __restrict__ out, int n8) {
    int i = blockIdx.x * blockDim.x + threadIdx.x;
    int stride = gridDim.x * blockDim.x;
    for (; i < n8; i += stride) {
        f32x4 v0 = *(const f32x4*)&in[(size_t)i * 8];
        f32x4 v1 = *(const f32x4*)&in[(size_t)i * 8 + 4];
        bf16x8 o;
        o[0] = (__bf16)v0[0]; o[1] = (__bf16)v0[1]; o[2] = (__bf16)v0[2]; o[3] = (__bf16)v0[3];
        o[4] = (__bf16)v1[0]; o[5] = (__bf16)v1[1]; o[6] = (__bf16)v1[2]; o[7] = (__bf16)v1[3];
        *(bf16x8*)&out[(size_t)i * 8] = o;
    }
}

// ---------- transpose + convert: dst[n][k] = (bf16) src[k][n] ----------
__global__ void transp_conv_kernel(const float* __restrict__ src, __bf16* __restrict__ dst,
                                   int K, int N) {
    __shared__ float tile[32][33];
    const int tx = threadIdx.x & 31;
    const int ty = threadIdx.x >> 5;
    const int k0 = blockIdx.x * 32;
    const int n0 = blockIdx.y * 32;
    #pragma unroll
    for (int i = 0; i < 32; i += 8)
        tile[ty + i][tx] = src[(size_t)(k0 + ty + i) * N + n0 + tx];
    __syncthreads();
    #pragma unroll
    for (int i = 0; i < 32; i += 8)
        dst[(size_t)(n0 + ty + i) * K + k0 + tx] = (__bf16)tile[tx][ty + i];
}

// ---------- 256x256 8-phase bf16 GEMM (T2+T3+T4+T5): C = A[M][K] * Bt[N][K]^T ----------
// Schedule identical to round 9 (proven 78 us). When !OUTF32, the epilogue also
// computes chunk-end scan sums E[b,k,ch] = sum_dt a^(63-dt) * u[t0+dt,ch] from the fp32
// accumulators (each (qr,sr) covers one 64-row chunk; dt = m*16+hi*4+j), replacing the
// separate scan1 pass (-64 MiB HBM re-read).
// NOTE (R8 lesson): do NOT spread staging 1-per-phase at 2-tiles-ahead with counted
// lgkm read-ahead — measured 78->130 us, FETCH +40% (L2 thrash + serialization).
// NOTE (R11 lesson): do NOT reg-stage A from fp32 x inside this loop — the 64 extra
// in-flight VGPRs spill to scratch (WRITE_SIZE +170 MB) and the compiler's auto-waits
// before the cvt drain the stage queue (MfmaUtil 36->12%, 80->213 us). Keep the
// separate conv pass.
template<int OUTF32>
__global__ __launch_bounds__(512, 2) void gemm256_kernel(
    const __bf16* __restrict__ A, const __bf16* __restrict__ Bt,
    __bf16* __restrict__ Obf, float* __restrict__ Of,
    const float* __restrict__ Ea, float* __restrict__ Ep,
    int M, int N, int K)
{
    __shared__ __bf16 lds[65536];   // A slots [0,32768), B slots [32768,65536)
    const int tid = threadIdx.x;
    const int wv = tid >> 6;          // 0..7
    const int l  = tid & 63;
    const int sr = wv >> 2;           // row slot 0..1
    const int sc = wv & 3;            // col slot 0..3
    const int lr = l & 15;
    const int lk = (l >> 4) * 8;
    const int xsw = (lr & 7) * 8;                 // read-side swizzle (elems)
    const int ak0 = lk ^ xsw, ak1 = (32 + lk) ^ xsw;
    const int rowBase = blockIdx.x * 256;
    const int colBase = blockIdx.y * 256;
    const int aOff = (sr * 64 + lr) * 64;         // A frag row base (elems, within half slot)
    const int bOff = (sc * 32 + lr) * 64;
    const int csw = ((l & 7) ^ (l >> 3)) * 8;     // source-side pre-swizzle (elems)
    const __bf16* aSrc0 = A  + (size_t)(rowBase + wv * 16 + (l >> 3)) * K + csw;
    const __bf16* bSrc0 = Bt + (size_t)(colBase + wv * 16 + (l >> 3)) * K + csw;

    f32x4 acc[2][2][4][2];
    #pragma unroll
    for (int a0 = 0; a0 < 2; a0++)
        #pragma unroll
        for (int b0 = 0; b0 < 2; b0++)
            #pragma unroll
            for (int m = 0; m < 4; m++)
                #pragma unroll
                for (int n = 0; n < 2; n++)
                    acc[a0][b0][m][n] = (f32x4){0.f, 0.f, 0.f, 0.f};

    bf16x8 aF0[4][2], aF1[4][2], bF[2][2];

#define GLD(s, d) __builtin_amdgcn_global_load_lds( \
        (const __attribute__((address_space(1))) void*)(s), \
        (__attribute__((address_space(3))) void*)(d), 16, 0, 0)
#define STAGE_A(buf, half, ktE) do { \
        const __bf16* s_ = aSrc0 + (size_t)(half) * 128 * K + (ktE); \
        __bf16* d_ = &lds[((buf) * 2 + (half)) * 8192 + wv * 1024]; \
        GLD(s_, d_); GLD(s_ + (size_t)8 * K, d_ + 512); } while (0)
#define STAGE_B(buf, half, ktE) do { \
        const __bf16* s_ = bSrc0 + (size_t)(half) * 128 * K + (ktE); \
        __bf16* d_ = &lds[32768 + ((buf) * 2 + (half)) * 8192 + wv * 1024]; \
        GLD(s_, d_); GLD(s_ + (size_t)8 * K, d_ + 512); } while (0)
#define LOADA(buf, qr, AF) do { \
        const __bf16* Ab_ = &lds[((buf) * 2 + (qr)) * 8192 + aOff]; \
        _Pragma("unroll") \
        for (int m = 0; m < 4; m++) { \
            AF[m][0] = *(const bf16x8*)&Ab_[m * 1024 + ak0]; \
            AF[m][1] = *(const bf16x8*)&Ab_[m * 1024 + ak1]; } } while (0)
#define LOADB(buf, qc) do { \
        const __bf16* Bb_ = &lds[32768 + ((buf) * 2 + (qc)) * 8192 + bOff]; \
        _Pragma("unroll") \
        for (int n = 0; n < 2; n++) { \
            bF[n][0] = *(const bf16x8*)&Bb_[n * 1024 + ak0]; \
            bF[n][1] = *(const bf16x8*)&Bb_[n * 1024 + ak1]; } } while (0)
#define MMQ(qr, qc, AF) do { \
        __builtin_amdgcn_s_setprio(1); \
        _Pragma("unroll") \
        for (int m = 0; m < 4; m++) \
            _Pragma("unroll") \
            for (int n = 0; n < 2; n++) { \
                acc[qr][qc][m][n] = __builtin_amdgcn_mfma_f32_16x16x32_bf16(AF[m][0], bF[n][0], acc[qr][qc][m][n], 0, 0, 0); \
                acc[qr][qc][m][n] = __builtin_amdgcn_mfma_f32_16x16x32_bf16(AF[m][1], bF[n][1], acc[qr][qc][m][n], 0, 0, 0); } \
        __builtin_amdgcn_s_setprio(0); } while (0)
// phase-start: pin loads above barrier; all-waves sync; drain own ds_reads; pin MFMA below
#define PH_BAR() do { __builtin_amdgcn_sched_barrier(0); __builtin_amdgcn_s_barrier(); \
        asm volatile("s_waitcnt lgkmcnt(0)" ::: "memory"); \
        __builtin_amdgcn_sched_barrier(0); } while (0)
#define PHEND() do { __builtin_amdgcn_sched_barrier(0); __builtin_amdgcn_s_barrier(); } while (0)
#define PHEND_W(cond) do { __builtin_amdgcn_sched_barrier(0); \
        if (cond) { asm volatile("s_waitcnt vmcnt(0)" ::: "memory"); } \
        else      { asm volatile("s_waitcnt vmcnt(4)" ::: "memory"); } \
        __builtin_amdgcn_s_barrier(); } while (0)

    const int NIT = K >> 7;   // 2 K-tiles (of 64) per iteration

    // prologue: stage K-tile 0 -> buf0, K-tile 1 -> buf1; wait K-tile 0 (leave 8 in flight)
    STAGE_A(0, 0, 0); STAGE_A(0, 1, 0); STAGE_B(0, 0, 0); STAGE_B(0, 1, 0);
    STAGE_A(1, 0, 64); STAGE_A(1, 1, 64); STAGE_B(1, 0, 64); STAGE_B(1, 1, 64);
    asm volatile("s_waitcnt vmcnt(8)" ::: "memory");
    __builtin_amdgcn_s_barrier();

    for (int it = 0; it < NIT; ++it) {
        const int ktOdd  = (2 * it + 1) * 64;   // this iter's odd K-tile (buf1 half1 fill)
        const int ktEv2  = (2 * it + 2) * 64;   // next even K-tile (buf0)
        const int ktOdd2 = (2 * it + 3) * 64;   // next odd K-tile (buf1 half0 fill)
        const bool last = (it == NIT - 1);
        // P1: Q(0,0) buf0 — loads A0 (8) + B0 (4)
        LOADA(0, 0, aF0); LOADB(0, 0);
        if (it > 0) STAGE_A(1, 1, ktOdd);
        PH_BAR(); MMQ(0, 0, aF0); PHEND();
        // P2: Q(1,0) buf0 — loads A1 (8), reuse bF
        LOADA(0, 1, aF1);
        if (it > 0) STAGE_B(1, 1, ktOdd);
        PH_BAR(); MMQ(1, 0, aF1); PHEND();
        // P3: Q(1,1) buf0 — loads B1 (4), reuse aF1
        LOADB(0, 1);
        if (!last) STAGE_B(0, 0, ktEv2);
        PH_BAR(); MMQ(1, 1, aF1); PHEND();
        // P4: Q(0,1) buf0 — no LDS reads; group wait (K-tile 2it+1 resident after this)
        if (!last) STAGE_A(0, 0, ktEv2);
        PH_BAR(); MMQ(0, 1, aF0); PHEND_W(last);
        // P5: Q(0,0) buf1
        LOADA(1, 0, aF0); LOADB(1, 0);
        if (!last) STAGE_A(0, 1, ktEv2);
        PH_BAR(); MMQ(0, 0, aF0); PHEND();
        // P6: Q(1,0) buf1
        LOADA(1, 1, aF1);
        if (!last) STAGE_B(0, 1, ktEv2);
        PH_BAR(); MMQ(1, 0, aF1); PHEND();
        // P7: Q(1,1) buf1
        LOADB(1, 1);
        if (!last) STAGE_B(1, 0, ktOdd2);
        PH_BAR(); MMQ(1, 1, aF1); PHEND();
        // P8: Q(0,1) buf1 — no LDS reads; group wait (K-tile 2it+2 resident after this)
        if (!last) STAGE_A(1, 0, ktOdd2);
        PH_BAR(); MMQ(0, 1, aF0); PHEND_W(last);
    }

    // epilogue: C/D layout col=lane&15, row=(lane>>4)*4+j [m89]
    #pragma unroll
    for (int qr = 0; qr < 2; qr++)
        #pragma unroll
        for (int qc = 0; qc < 2; qc++)
            #pragma unroll
            for (int m = 0; m < 4; m++)
                #pragma unroll
                for (int n = 0; n < 2; n++)
                    #pragma unroll
                    for (int j = 0; j < 4; j++) {
                        int row = rowBase + qr * 128 + sr * 64 + m * 16 + (l >> 4) * 4 + j;
                        int col = colBase + qc * 128 + sc * 32 + n * 16 + lr;
                        size_t idx = (size_t)row * N + col;
                        if constexpr (OUTF32) Of[idx] = acc[qr][qc][m][n][j];
                        else                  Obf[idx] = (__bf16)acc[qr][qc][m][n][j];
                    }

    // fused scan1: E[b,k,ch] = sum_{dt=0}^{63} a_ch^(63-dt) * u[t0+dt,ch].
    // Thread's dt = m*16 + hi*4 + j (hi = l>>4); weight chain descending dt:
    // w starts at a^(4*(3-hi)) (m=3,j=3), *= a per j-step, *= a^12 per m-boundary.
    if constexpr (!OUTF32) {
        const int hi = l >> 4;
        const int bb = rowBase >> 12;            // row / TT
        #pragma unroll
        for (int qr = 0; qr < 2; qr++) {
            const int r0 = rowBase + qr * 128 + sr * 64;
            const int kch = (r0 & (TT - 1)) >> 6;          // chunk index within batch
            #pragma unroll
            for (int qc = 0; qc < 2; qc++)
                #pragma unroll
                for (int n = 0; n < 2; n++) {
                    const int ch = colBase + qc * 128 + sc * 32 + n * 16 + lr;
                    const float av = Ea[ch];
                    const float a2 = av * av, a4 = a2 * a2;
                    const float a12 = a4 * a4 * a4;
                    float w = 1.f;
                    if (hi < 3) w *= a4;
                    if (hi < 2) w *= a4;
                    if (hi < 1) w *= a4;                   // a^(4*(3-hi))
                    float e = 0.f;
                    #pragma unroll
                    for (int m = 3; m >= 0; --m) {
                        #pragma unroll
                        for (int j = 3; j >= 0; --j) {
                            e += w * acc[qr][qc][m][n][j];
                            w *= av;
                        }
                        w *= a12;                          // jump 16-3-1 = 12 in exponent
                    }
                    e += __shfl_xor(e, 16);
                    e += __shfl_xor(e, 32);
                    if (hi == 0)
                        Ep[((size_t)(bb * NC + kch)) * DH + ch] = e;
                }
        }
    }
#undef GLD
#undef STAGE_A
#undef STAGE_B
#undef LOADA
#undef LOADB
#undef MMQ
#undef PH_BAR
#undef PHEND
#undef PHEND_W
}

// ---------- scan pass 2: combine chunk carries ----------
__global__ void scan2_kernel(const float* __restrict__ E, const float* __restrict__ a,
                             float* __restrict__ Cc) {
    int g = blockIdx.x * blockDim.x + threadIdx.x;
    int ch = g & (DH - 1);
    int b = g >> 10;
    float av = a[ch];
    float aL = av;
    #pragma unroll
    for (int i = 0; i < 6; i++) aL *= aL;            // a^64 = a^CL
    float carry = 0.f;
    for (int k = 0; k < NC; k++) {
        size_t idx = ((size_t)(b * NC + k)) * DH + ch;
        Cc[idx] = carry;
        carry = aL * carry + E[idx];
    }
}

// ---------- scan pass 3: recompute local scan + apply carry, write bf16 in place ----------
__global__ void scan3_kernel(__bf16* __restrict__ u, const float* __restrict__ a,
                             const float* __restrict__ Cc) {
    int g = blockIdx.x * blockDim.x + threadIdx.x;
    int c4 = g & 255;
    int rest = g >> 8;
    int k = rest & (NC - 1);
    int b = rest >> 6;
    int ch = c4 * 4;
    f32x4 av = { a[ch], a[ch + 1], a[ch + 2], a[ch + 3] };
    f32x4 p = *(const f32x4*)&Cc[((size_t)(b * NC + k)) * DH + ch];
    f32x4 h = {0.f, 0.f, 0.f, 0.f};
    size_t base = ((size_t)(b * TT + k * CL)) * DH + ch;
    for (int t = 0; t < CL; t++) {
        size_t idx = base + (size_t)t * DH;
        bf16x4 v = *(bf16x4*)&u[idx];
        h[0] = h[0] * av[0] + (float)v[0];
        h[1] = h[1] * av[1] + (float)v[1];
        h[2] = h[2] * av[2] + (float)v[2];
        h[3] = h[3] * av[3] + (float)v[3];
        p[0] *= av[0]; p[1] *= av[1]; p[2] *= av[2]; p[3] *= av[3];
        bf16x4 o;
        o[0] = (__bf16)(h[0] + p[0]);
        o[1] = (__bf16)(h[1] + p[1]);
        o[2] = (__bf16)(h[2] + p[2]);
        o[3] = (__bf16)(h[3] + p[3]);
        *(bf16x4*)&u[idx] = o;
    }
}

extern "C" void kernel_launch(void* const* d_in, const int* in_sizes, int n_in,
                              void* d_out, int out_size, void* d_ws, size_t ws_size,
                              hipStream_t stream) {
    const float* x = (const float*)d_in[0];
    const float* a = (const float*)d_in[1];
    const float* b = (const float*)d_in[2];
    const float* c = (const float*)d_in[3];
    float* y = (float*)d_out;

    // workspace: 68 MiB (proven safe)
    char* ws = (char*)d_ws;
    size_t off = 0;
    __bf16* u  = (__bf16*)(ws + off); off += (size_t)M1 * DH * 2;   // 64 MiB
    __bf16* bT = (__bf16*)(ws + off); off += (size_t)DI * DH * 2;   // 2 MiB
    __bf16* cT = (__bf16*)(ws + off); off += (size_t)DH * DO * 2;   // 2 MiB
    if (ws_size < off) return;

    // scratch inside d_out (dead before gemm2 writes y)
    __bf16* xbf = (__bf16*)d_out;
    float*  E   = (float*)((char*)d_out + (size_t)M1 * DI * 2);
    float*  Cc  = E + (size_t)BS * NC * DH;

    conv_bf16_kernel<<<2048, 256, 0, stream>>>(x, xbf, (M1 * DI) / 8);
    transp_conv_kernel<<<dim3(DI / 32, DH / 32), 256, 0, stream>>>(b, bT, DI, DH);
    transp_conv_kernel<<<dim3(DH / 32, DO / 32), 256, 0, stream>>>(c, cT, DH, DO);
    // u = bf16(x @ b), with fused chunk-end scan sums E (replaces scan1)
    gemm256_kernel<0><<<dim3(M1 / 256, DH / 256), 512, 0, stream>>>(xbf, bT, u, nullptr, a, E, M1, DH, DI);
    // chunked diagonal linear scan over T (in place on u)
    scan2_kernel<<<(BS * DH) / 256, 256, 0, stream>>>(E, a, Cc);
    scan3_kernel<<<(BS * NC * (DH / 4)) / 256, 256, 0, stream>>>(u, a, Cc);
    // y = hs @ c
    gemm256_kernel<1><<<dim3(M1 / 256, DO / 256), 512, 0, stream>>>(u, cT, nullptr, y, nullptr, nullptr, M1, DO, DH);
}